// Round 2
// baseline (581.784 us; speedup 1.0000x reference)
//
#include <hip/hip_runtime.h>

#define LL 16384
#define HH 128
#define WW 128
#define CC 64
#define NH 8
#define EPSF 1e-7f

// ---------------- zero scratch (KV/KS accumulators) ----------------
__global__ void zero_kernel(float* __restrict__ p, int n) {
    int i = blockIdx.x * 256 + threadIdx.x;
    if (i < n) p[i] = 0.f;
}

// ---------------- Kernel A: qkv 1x1 conv + bias (+relu on q,k) ----------------
// grid (64 pixel-blocks, B, 3 sections), block 256
__global__ void qkv_kernel(const float* __restrict__ x, const float* __restrict__ w,
                           const float* __restrict__ bias,
                           float* __restrict__ q, float* __restrict__ k, float* __restrict__ v) {
    const int pix = blockIdx.x * 256 + threadIdx.x;
    const int b   = blockIdx.y;
    const int sec = blockIdx.z;

    float xr[64];
    const float* xb = x + (size_t)b * CC * LL + pix;
#pragma unroll
    for (int c = 0; c < 64; ++c) xr[c] = xb[(size_t)c * LL];

    float* dst = (sec == 0) ? q : (sec == 1) ? k : v;
    const bool do_relu = (sec < 2);

    for (int ol = 0; ol < 64; ++ol) {
        const int o = sec * 64 + ol;
        const float* wr = w + o * 64;           // wave-uniform -> scalar loads
        float a0 = 0.f, a1 = 0.f, a2 = 0.f, a3 = 0.f;
#pragma unroll
        for (int c = 0; c < 64; c += 4) {
            a0 += xr[c]     * wr[c];
            a1 += xr[c + 1] * wr[c + 1];
            a2 += xr[c + 2] * wr[c + 2];
            a3 += xr[c + 3] * wr[c + 3];
        }
        float acc = (a0 + a1) + (a2 + a3) + bias[o];
        if (do_relu) acc = fmaxf(acc, 0.f);
        dst[(size_t)(b * 64 + ol) * LL + pix] = acc;
    }
}

// ---------------- Kernel B: KV = K_unfold^T @ V and Ksum, per (b,h) ----------------
// grid (16 row-chunks, NH, B), block 256: thread -> (c = tid>>5, lane s = tid&31)
__global__ void kv_kernel(const float* __restrict__ k, const float* __restrict__ v,
                          float* __restrict__ KV, float* __restrict__ KS) {
    const int chunk = blockIdx.x;
    const int h = blockIdx.y;
    const int b = blockIdx.z;
    const int tid = threadIdx.x;
    const int c = tid >> 5;
    const int s = tid & 31;

    const float* kc = k + ((size_t)(b * 64) + 8 * h + c) * LL;
    const float* vb = v + ((size_t)(b * 64) + 8 * h) * LL;

    float kv[9][8] = {{0.f}};
    float ks[9] = {0.f};

    for (int r = 0; r < 8; ++r) {
        const int y = chunk * 8 + r;
        for (int g = 0; g < 4; ++g) {
            const int col = s + 32 * g;
            float vv[8];
#pragma unroll
            for (int cp = 0; cp < 8; ++cp) vv[cp] = vb[(size_t)cp * LL + y * WW + col];
            float k9[9];
#pragma unroll
            for (int dy = -1; dy <= 1; ++dy)
#pragma unroll
                for (int dx = -1; dx <= 1; ++dx) {
                    const int yy = y + dy, xx = col + dx;
                    const bool ok = (yy >= 0 && yy < HH && xx >= 0 && xx < WW);
                    k9[(dy + 1) * 3 + (dx + 1)] = ok ? kc[yy * WW + xx] : 0.f;
                }
#pragma unroll
            for (int p = 0; p < 9; ++p) {
                ks[p] += k9[p];
#pragma unroll
                for (int cp = 0; cp < 8; ++cp) kv[p][cp] += k9[p] * vv[cp];
            }
        }
    }

    // reduce across the 32 lanes that share c (masks <=16 stay inside the 32-group)
#pragma unroll
    for (int p = 0; p < 9; ++p) {
#pragma unroll
        for (int m = 16; m >= 1; m >>= 1) ks[p] += __shfl_xor(ks[p], m);
#pragma unroll
        for (int cp = 0; cp < 8; ++cp) {
#pragma unroll
            for (int m = 16; m >= 1; m >>= 1) kv[p][cp] += __shfl_xor(kv[p][cp], m);
        }
    }

    if (s == 0) {
        const int base = ((b * NH + h) * 8 + c) * 9;
#pragma unroll
        for (int p = 0; p < 9; ++p) {
            atomicAdd(&KS[base + p], ks[p]);
#pragma unroll
            for (int cp = 0; cp < 8; ++cp)
                atomicAdd(&KV[(base + p) * 8 + cp], kv[p][cp]);
        }
    }
}

// ---------------- Kernel C: out = (Q_unfold @ KV) / (Q_unfold @ Ksum + EPS) ----------------
// grid (128 rows, NH, B), block 128 (thread = column)
__global__ void attn_kernel(const float* __restrict__ q, const float* __restrict__ KV,
                            const float* __restrict__ KS, float* __restrict__ ao) {
    const int y = blockIdx.x;
    const int h = blockIdx.y;
    const int b = blockIdx.z;
    const int col = threadIdx.x;

    float out[8] = {0.f};
    float den = 0.f;
    const int kvbase = (b * NH + h) * 8;

    for (int c = 0; c < 8; ++c) {
        const float* qc = q + ((size_t)(b * 64) + 8 * h + c) * LL;
        float q9[9];
#pragma unroll
        for (int dy = -1; dy <= 1; ++dy)
#pragma unroll
            for (int dx = -1; dx <= 1; ++dx) {
                const int yy = y + dy, xx = col + dx;
                const bool ok = (yy >= 0 && yy < HH && xx >= 0 && xx < WW);
                q9[(dy + 1) * 3 + (dx + 1)] = ok ? qc[yy * WW + xx] : 0.f;
            }
        const float* kvr = KV + ((size_t)(kvbase + c) * 9) * 8;  // wave-uniform -> scalar loads
        const float* ksr = KS + (size_t)(kvbase + c) * 9;
#pragma unroll
        for (int p = 0; p < 9; ++p) {
            const float qv = q9[p];
            den += qv * ksr[p];
#pragma unroll
            for (int cp = 0; cp < 8; ++cp) out[cp] += qv * kvr[p * 8 + cp];
        }
    }
    const float inv = 1.f / (den + EPSF);
    const int pix = y * WW + col;
#pragma unroll
    for (int cp = 0; cp < 8; ++cp)
        ao[((size_t)(b * 64) + h * 8 + cp) * LL + pix] = out[cp] * inv;
}

// ---------------- Kernel D: 3x3 conv 64->64 + bias ----------------
// grid (128 rows, B), block 256: thread -> (col = tid&127, c_out half = tid>>7)
__global__ void conv_kernel(const float* __restrict__ ao, const float* __restrict__ w,
                            const float* __restrict__ bias, float* __restrict__ out) {
    const int y = blockIdx.x;
    const int b = blockIdx.y;
    const int col  = threadIdx.x & 127;
    const int half = threadIdx.x >> 7;

    float acc[32] = {0.f};
    const float* aob = ao + (size_t)b * 64 * LL;

    for (int ci = 0; ci < 64; ++ci) {
        float a9[9];
#pragma unroll
        for (int dy = -1; dy <= 1; ++dy)
#pragma unroll
            for (int dx = -1; dx <= 1; ++dx) {
                const int yy = y + dy, xx = col + dx;
                const bool ok = (yy >= 0 && yy < HH && xx >= 0 && xx < WW);
                a9[(dy + 1) * 3 + (dx + 1)] = ok ? aob[(size_t)ci * LL + yy * WW + xx] : 0.f;
            }
#pragma unroll
        for (int co = 0; co < 32; ++co) {
            const float* wr = w + (((half * 32 + co) * 64 + ci) * 9);  // wave-uniform
            float t = a9[0] * wr[0] + a9[1] * wr[1] + a9[2] * wr[2]
                    + a9[3] * wr[3] + a9[4] * wr[4] + a9[5] * wr[5]
                    + a9[6] * wr[6] + a9[7] * wr[7] + a9[8] * wr[8];
            acc[co] += t;
        }
    }
    const int pix = y * WW + col;
#pragma unroll
    for (int co = 0; co < 32; ++co) {
        const int o = half * 32 + co;
        out[((size_t)b * 64 + o) * LL + pix] = acc[co] + bias[o];
    }
}

extern "C" void kernel_launch(void* const* d_in, const int* in_sizes, int n_in,
                              void* d_out, int out_size, void* d_ws, size_t ws_size,
                              hipStream_t stream) {
    const float* x      = (const float*)d_in[0];
    const float* qkv_w  = (const float*)d_in[1];
    const float* qkv_b  = (const float*)d_in[2];
    const float* proj_w = (const float*)d_in[3];
    const float* proj_b = (const float*)d_in[4];
    float* out = (float*)d_out;
    float* ws  = (float*)d_ws;

    const size_t n1 = (size_t)4 * 64 * LL;      // one B*C*L fp32 plane set
    float* qb  = ws;
    float* kb  = ws + n1;
    float* vb  = ws + 2 * n1;
    float* aob = ws + 3 * n1;
    float* KV  = ws + 4 * n1;                   // 4*8*8*9*8 = 18432 floats
    float* KS  = KV + 4 * 8 * 8 * 9 * 8;        // 4*8*8*9  = 2304 floats

    const int nzero = 4 * 8 * 8 * 9 * 8 + 4 * 8 * 8 * 9;
    zero_kernel<<<(nzero + 255) / 256, 256, 0, stream>>>(KV, nzero);

    qkv_kernel<<<dim3(64, 4, 3), 256, 0, stream>>>(x, qkv_w, qkv_b, qb, kb, vb);
    kv_kernel<<<dim3(16, NH, 4), 256, 0, stream>>>(kb, vb, KV, KS);
    attn_kernel<<<dim3(128, NH, 4), 128, 0, stream>>>(qb, KV, KS, aob);
    conv_kernel<<<dim3(128, 4), 256, 0, stream>>>(aob, proj_w, proj_b, out);
}